// Round 5
// baseline (252.458 us; speedup 1.0000x reference)
//
#include <hip/hip_runtime.h>
#include <hip/hip_bf16.h>

// FocusAttention: B=8, L=S=1024, H=8, E=D=64
// qt = phi_p(q), kt = phi_p(k)  (power-norm p=2 over E)
// A = softmax(c * s^2) rowwise, c = sqrt(sum s^2 / sum s^4) (full-row const
// -> online softmax impossible; two passes over K, recompute QK^T in pass 2).
// out = A @ v, [B,L,H,D] fp32.
//
// R5: R4 still latency-bound (Mfma 14, VALU 42, Occ 33; TLP hard-capped at
// 4 waves/SIMD by problem shape). K/V are L2-resident (FETCH 12MB after XCD
// swizzle) -> LDS staging + 33 barriers are pure overhead. Changes:
//  - ALL B-fragments (K pass1+pass2, V pass2) read direct from global/L2;
//    ZERO __syncthreads in attn; LDS = per-wave wbuf transpose only
//  - deep unroll -> compiler pipelines loads across tiles (no barrier fences)
//  - XOR chunk swizzle dropped (only served LDS/glds); linear layout
//  - phi vectorized: float4 loads, 4 rows/wave, f16x4 stores

#define B_ 8
#define L_ 1024
#define H_ 8
#define E_ 64
#define S_ 1024
#define D_ 64
#define BH_ 64

typedef _Float16 f16_t;
typedef _Float16 f16x8 __attribute__((ext_vector_type(8)));
typedef _Float16 f16x4v __attribute__((ext_vector_type(4)));
typedef float f32x4 __attribute__((ext_vector_type(4)));

#define MFMA16F(a, b, c) __builtin_amdgcn_mfma_f32_16x16x32_f16(a, b, c, 0, 0, 0)

// ---------------------------------------------------------------------------
// K1: phi_p rows, 4 rows per wave (16 lanes x 4 elems each), float4 in,
// f16x4 out to [B,H,row,E] (linear, no swizzle).
// ---------------------------------------------------------------------------
__global__ __launch_bounds__(256) void phi_kernel(
    const float* __restrict__ q, const float* __restrict__ k,
    f16_t* __restrict__ qf, f16_t* __restrict__ kf) {
  int row = blockIdx.x * 16 + (threadIdx.x >> 4);
  int p = threadIdx.x & 15;
  const float* src;
  f16_t* dst;
  int r = row;
  if (r < B_ * L_ * H_) { src = q; dst = qf; }
  else { r -= B_ * L_ * H_; src = k; dst = kf; }
  int b = r >> 13;            // r / (L*H)
  int l = (r >> 3) & 1023;
  int h = r & 7;
  float4 x = ((const float4*)(src + (size_t)r * 64))[p];
  float s0 = fmaxf(x.x, 0.f) * fmaxf(x.x, 0.f);
  float s1 = fmaxf(x.y, 0.f) * fmaxf(x.y, 0.f);
  float s2 = fmaxf(x.z, 0.f) * fmaxf(x.z, 0.f);
  float s3 = fmaxf(x.w, 0.f) * fmaxf(x.w, 0.f);
  float sum2 = (s0 + s1) + (s2 + s3);
  float sum4 = fmaf(s0, s0, s1 * s1) + fmaf(s2, s2, s3 * s3);
#pragma unroll
  for (int off = 1; off < 16; off <<= 1) {  // xor<16 stays in the 16-lane group
    sum2 += __shfl_xor(sum2, off, 64);
    sum4 += __shfl_xor(sum4, off, 64);
  }
  float sc = (sum4 > 0.f) ? sqrtf(sum2 / sum4) : 0.f;
  f16x4v o = {(f16_t)(sc * s0), (f16_t)(sc * s1), (f16_t)(sc * s2), (f16_t)(sc * s3)};
  *(f16x4v*)(dst + ((size_t)(b * H_ + h) * 1024 + l) * 64 + p * 4) = o;
}

// ---------------------------------------------------------------------------
// K1b: V [B,S,H,D] fp32 -> vt f16 tiled [bh][st=S/32][64 d][32 s]
// (PV B-frag loads from vt are fully coalesced 16B/lane)
// ---------------------------------------------------------------------------
__global__ __launch_bounds__(256) void vt_kernel(
    const float* __restrict__ v, f16_t* __restrict__ vt) {
  __shared__ float tile[32][68];
  int bh = blockIdx.x >> 5;
  int st = blockIdx.x & 31;
  int b = bh >> 3, h = bh & 7;
  int t = threadIdx.x;
  int sl = t >> 3, dp = t & 7;
  const float* src = v + (((size_t)(b * S_ + st * 32 + sl) * H_ + h) * D_) + dp * 8;
  float4 f0 = ((const float4*)src)[0];
  float4 f1 = ((const float4*)src)[1];
  *(float4*)&tile[sl][dp * 8] = f0;
  *(float4*)&tile[sl][dp * 8 + 4] = f1;
  __syncthreads();
  int d = t >> 2, sc = t & 3;
  f16_t tmp[8];
#pragma unroll
  for (int j = 0; j < 8; ++j) tmp[j] = (f16_t)tile[sc * 8 + j][d];
  f16_t* dst = vt + (((size_t)bh * 32 + st) * 64 + d) * 32 + sc * 8;
  *(uint4*)dst = *(const uint4*)tmp;
}

// ---------------------------------------------------------------------------
// K2: fused two-pass attention, BARRIER-FREE. Block = (b,h) x 64 q-rows;
// 4 waves x 16 rows. All K/V B-frags direct from global (L2-resident after
// XCD swizzle). LDS: per-wave w transpose buffer only (wave-local ordering).
// MFMA layouts (m89/m91): C/D col=lane&15, row=(lane>>4)*4+reg;
// A[m=lane&15][k=(lane>>4)*8+j]; B[k=(lane>>4)*8+j][n=lane&15].
// ---------------------------------------------------------------------------
__global__ __launch_bounds__(256, 4) void attn_kernel(
    const f16_t* __restrict__ qf, const f16_t* __restrict__ kf,
    const f16_t* __restrict__ vt, float* __restrict__ out) {
  __shared__ __align__(16) f16_t wbuf[4][16 * 40];  // per-wave, PAD 40

  int bh = blockIdx.x & 63;   // XCD swizzle: all q-blocks of a head co-located
  int qb = blockIdx.x >> 6;
  int b = bh >> 3, h = bh & 7;
  int tid = threadIdx.x;
  int wave = tid >> 6, lane = tid & 63;
  int g = lane >> 4, n = lane & 15;

  const f16_t* qf_b = qf + ((size_t)bh * L_ + qb * 64) * 64;
  const f16_t* kf_b = kf + (size_t)bh * S_ * 64;
  const f16_t* vt_b = vt + (size_t)bh * 32 * 2048;

  // Q A-fragments (loop-invariant): row wave*16+n, k-chunks g and g+4
  int arow = wave * 16 + n;
  f16x8 qa0 = *(const f16x8*)(qf_b + arow * 64 + g * 8);
  f16x8 qa1 = *(const f16x8*)(qf_b + arow * 64 + 32 + g * 8);

  int koff = n * 64 + g * 8;  // B-frag: row n (row n+16 at +1024), k-chunk g
  int voff = n * 32 + g * 8;  // V B-frag within [64d][32s] tile (+dg*512)

  const f32x4 fzero = {0.f, 0.f, 0.f, 0.f};
  float acc2[4] = {0, 0, 0, 0}, acc4[4] = {0, 0, 0, 0}, mx[4] = {0, 0, 0, 0};

  // ---- PASS 1: row stats (K direct from L2, fully pipelined) ----
#pragma unroll 4
  for (int t = 0; t < 32; ++t) {
    const f16_t* kg = kf_b + t * 2048;
    f16x8 b00 = *(const f16x8*)(kg + koff);
    f16x8 b01 = *(const f16x8*)(kg + koff + 32);
    f16x8 b10 = *(const f16x8*)(kg + koff + 1024);
    f16x8 b11 = *(const f16x8*)(kg + koff + 1056);
    f32x4 sc0 = MFMA16F(qa0, b00, fzero);
    sc0 = MFMA16F(qa1, b01, sc0);
    f32x4 sc1 = MFMA16F(qa0, b10, fzero);
    sc1 = MFMA16F(qa1, b11, sc1);
#pragma unroll
    for (int r = 0; r < 4; ++r) {
      float s = sc0[r], s2 = s * s;
      acc2[r] += s2; acc4[r] = fmaf(s2, s2, acc4[r]); mx[r] = fmaxf(mx[r], s2);
      s = sc1[r]; s2 = s * s;
      acc2[r] += s2; acc4[r] = fmaf(s2, s2, acc4[r]); mx[r] = fmaxf(mx[r], s2);
    }
  }
#pragma unroll
  for (int off = 1; off < 16; off <<= 1)
#pragma unroll
    for (int r = 0; r < 4; ++r) {
      acc2[r] += __shfl_xor(acc2[r], off, 64);
      acc4[r] += __shfl_xor(acc4[r], off, 64);
      mx[r] = fmaxf(mx[r], __shfl_xor(mx[r], off, 64));
    }
  float c2[4], cm2[4];
  const float LOG2E = 1.44269504f;
#pragma unroll
  for (int r = 0; r < 4; ++r) {
    float cr = (acc4[r] > 0.f) ? (sqrtf(acc2[r] / acc4[r]) * LOG2E) : 0.f;
    c2[r] = cr;
    cm2[r] = cr * mx[r];
  }

  // ---- PASS 2: scores -> w -> PV, barrier-free ----
  f32x4 pv[4];
#pragma unroll
  for (int dg = 0; dg < 4; ++dg) pv[dg] = fzero;
  float den[4] = {0, 0, 0, 0};
  f16_t* wb = wbuf[wave];

#pragma unroll 2
  for (int t = 0; t < 32; ++t) {
    const f16_t* kg = kf_b + t * 2048;
    const f16_t* vg = vt_b + t * 2048;
    // V B-frags issued early (independent of score chain)
    f16x8 vb[4];
#pragma unroll
    for (int dg = 0; dg < 4; ++dg)
      vb[dg] = *(const f16x8*)(vg + voff + dg * 512);
    f16x8 b00 = *(const f16x8*)(kg + koff);
    f16x8 b01 = *(const f16x8*)(kg + koff + 32);
    f16x8 b10 = *(const f16x8*)(kg + koff + 1024);
    f16x8 b11 = *(const f16x8*)(kg + koff + 1056);
    f32x4 sc0 = MFMA16F(qa0, b00, fzero);
    sc0 = MFMA16F(qa1, b01, sc0);
    f32x4 sc1 = MFMA16F(qa0, b10, fzero);
    sc1 = MFMA16F(qa1, b11, sc1);
    // w = 2^(c2*s^2 - c2*M); C-layout -> A-layout via per-wave LDS
#pragma unroll
    for (int r = 0; r < 4; ++r) {
      float w0 = exp2f(fmaf(sc0[r] * sc0[r], c2[r], -cm2[r]));
      float w1 = exp2f(fmaf(sc1[r] * sc1[r], c2[r], -cm2[r]));
      den[r] += w0 + w1;
      wb[(g * 4 + r) * 40 + n] = (f16_t)w0;
      wb[(g * 4 + r) * 40 + 16 + n] = (f16_t)w1;
    }
    f16x8 wa = *(const f16x8*)(wb + n * 40 + g * 8);  // same-wave, in-order
#pragma unroll
    for (int dg = 0; dg < 4; ++dg) pv[dg] = MFMA16F(wa, vb[dg], pv[dg]);
  }
  // denominator reduce + normalize + store [B,L,H,D]
#pragma unroll
  for (int off = 1; off < 16; off <<= 1)
#pragma unroll
    for (int r = 0; r < 4; ++r) den[r] += __shfl_xor(den[r], off, 64);
#pragma unroll
  for (int r = 0; r < 4; ++r) {
    float inv = 1.f / den[r];
    int l = qb * 64 + wave * 16 + g * 4 + r;
    float* op = out + (((size_t)b * L_ + l) * H_ + h) * D_;
#pragma unroll
    for (int dg = 0; dg < 4; ++dg) op[dg * 16 + n] = pv[dg][r] * inv;
  }
}

extern "C" void kernel_launch(void* const* d_in, const int* in_sizes, int n_in,
                              void* d_out, int out_size, void* d_ws, size_t ws_size,
                              hipStream_t stream) {
  const float* q = (const float*)d_in[0];
  const float* k = (const float*)d_in[1];
  const float* v = (const float*)d_in[2];
  // d_in[3] (attn_mask) is all-False -> unused
  float* out = (float*)d_out;

  const size_t NE = (size_t)B_ * L_ * H_ * E_;  // 4,194,304 elems
  f16_t* qf = (f16_t*)d_ws;                     // ws usage: 3*NE*2B = 24 MB
  f16_t* kf = qf + NE;
  f16_t* vt = kf + NE;

  phi_kernel<<<(2 * B_ * L_ * H_) / 16, 256, 0, stream>>>(q, k, qf, kf);
  vt_kernel<<<BH_ * (S_ / 32), 256, 0, stream>>>(v, vt);
  attn_kernel<<<BH_ * (L_ / 64), 256, 0, stream>>>(qf, kf, vt, out);
}

// Round 6
// 161.941 us; speedup vs baseline: 1.5590x; 1.5590x over previous
//
#include <hip/hip_runtime.h>
#include <hip/hip_bf16.h>

// FocusAttention: B=8, L=S=1024, H=8, E=D=64
// A = softmax(c * s^2) rowwise, c = sqrt(sum s^2 / sum s^4) (full-row const
// -> two passes over K; recompute QK^T in pass 2). out = A @ v, fp32.
//
// R6: R5 (no-LDS) regressed 69->153us: compiler didn't pipeline direct L2
// loads (VGPR stayed 52); revert to R4 glds structure. R4/R5 counters show
// VALU-issue ~29us / MFMA ~10us invariant -> attack the VALU stream:
//  - raw v_exp_f32 (__builtin_amdgcn_exp2f): 8 libm instrs -> 1
//  - stats/weight math as f32x4 vector ops -> v_pk_*_f32 (2x fewer instrs)
//  - phi+vt fused into one prep kernel (3->2 dispatches)
// Kept: fp16 operands (absmax 0.078<0.095), XCD swizzle (FETCH 139->12MB),
// XOR chunk swizzle for glds lane-linear staging.

#define B_ 8
#define L_ 1024
#define H_ 8
#define E_ 64
#define S_ 1024
#define D_ 64
#define BH_ 64

typedef _Float16 f16_t;
typedef _Float16 f16x8 __attribute__((ext_vector_type(8)));
typedef _Float16 f16x4v __attribute__((ext_vector_type(4)));
typedef float f32x4 __attribute__((ext_vector_type(4)));

#define MFMA16F(a, b, c) __builtin_amdgcn_mfma_f32_16x16x32_f16(a, b, c, 0, 0, 0)
#define GLDS16(g, l)                                                        \
  __builtin_amdgcn_global_load_lds(                                         \
      (const __attribute__((address_space(1))) void*)(g),                   \
      (__attribute__((address_space(3))) void*)(l), 16, 0, 0)

#if __has_builtin(__builtin_amdgcn_exp2f)
#define EXP2(x) __builtin_amdgcn_exp2f(x)
#else
#define EXP2(x) exp2f(x)
#endif

// ---------------------------------------------------------------------------
// prep: blocks [0,8192) = phi_p on q,k rows (4 rows/wave, float4 loads,
// f16x4 swizzled stores); blocks [8192,10240) = V transpose to
// vt[bh][st=S/32][64 d][32 s] f16.
// XOR chunk swizzle: 8-elem chunk c of row l stored at chunk c^(l&7).
// ---------------------------------------------------------------------------
__global__ __launch_bounds__(256) void prep_kernel(
    const float* __restrict__ q, const float* __restrict__ k,
    const float* __restrict__ v, f16_t* __restrict__ qf,
    f16_t* __restrict__ kf, f16_t* __restrict__ vt) {
  __shared__ float tile[32][68];
  int bid = blockIdx.x;
  if (bid < 8192) {
    int row = bid * 16 + (threadIdx.x >> 4);
    int p = threadIdx.x & 15;
    const float* src;
    f16_t* dst;
    int r = row;
    if (r < B_ * L_ * H_) { src = q; dst = qf; }
    else { r -= B_ * L_ * H_; src = k; dst = kf; }
    int b = r >> 13;            // r / (L*H)
    int l = (r >> 3) & 1023;
    int h = r & 7;
    float4 x = ((const float4*)(src + (size_t)r * 64))[p];
    float s0 = fmaxf(x.x, 0.f) * fmaxf(x.x, 0.f);
    float s1 = fmaxf(x.y, 0.f) * fmaxf(x.y, 0.f);
    float s2 = fmaxf(x.z, 0.f) * fmaxf(x.z, 0.f);
    float s3 = fmaxf(x.w, 0.f) * fmaxf(x.w, 0.f);
    float sum2 = (s0 + s1) + (s2 + s3);
    float sum4 = fmaf(s0, s0, s1 * s1) + fmaf(s2, s2, s3 * s3);
#pragma unroll
    for (int off = 1; off < 16; off <<= 1) {
      sum2 += __shfl_xor(sum2, off, 64);
      sum4 += __shfl_xor(sum4, off, 64);
    }
    float sc = (sum4 > 0.f) ? sqrtf(sum2 / sum4) : 0.f;
    f16x4v o = {(f16_t)(sc * s0), (f16_t)(sc * s1), (f16_t)(sc * s2),
                (f16_t)(sc * s3)};
    int c = p >> 1, e = (p & 1) * 4;
    int col = (((c ^ (l & 7)) << 3) | e);
    *(f16x4v*)(dst + ((size_t)(b * H_ + h) * 1024 + l) * 64 + col) = o;
  } else {
    int vb = bid - 8192;
    int bh = vb >> 5;
    int st = vb & 31;
    int b = bh >> 3, h = bh & 7;
    int t = threadIdx.x;
    int sl = t >> 3, dp = t & 7;
    const float* src =
        v + (((size_t)(b * S_ + st * 32 + sl) * H_ + h) * D_) + dp * 8;
    float4 f0 = ((const float4*)src)[0];
    float4 f1 = ((const float4*)src)[1];
    *(float4*)&tile[sl][dp * 8] = f0;
    *(float4*)&tile[sl][dp * 8 + 4] = f1;
    __syncthreads();
    int d = t >> 2, sc = t & 3;
    f16_t tmp[8];
#pragma unroll
    for (int j = 0; j < 8; ++j) tmp[j] = (f16_t)tile[sc * 8 + j][d];
    f16_t* dst = vt + (((size_t)bh * 32 + st) * 64 + d) * 32 + sc * 8;
    *(uint4*)dst = *(const uint4*)tmp;
  }
}

// ---------------------------------------------------------------------------
// K2: fused two-pass attention. Block = (b,h) x 64 q-rows; 4 waves x 16 rows.
// Pass 1: barrier-free, K B-frags direct from global (L2-resident).
// Pass 2: 32-row K+V tiles, double-buffered glds, 1 barrier/tile.
// Stats & weight math vectorized (v_pk_*_f32); raw v_exp_f32.
// MFMA layouts (m89/m91): C/D col=lane&15, row=(lane>>4)*4+reg;
// A[m=lane&15][k=(lane>>4)*8+j]; B[k=(lane>>4)*8+j][n=lane&15].
// ---------------------------------------------------------------------------
__global__ __launch_bounds__(256, 4) void attn_kernel(
    const f16_t* __restrict__ qf, const f16_t* __restrict__ kf,
    const f16_t* __restrict__ vt, float* __restrict__ out) {
  __shared__ __align__(16) f16_t k_t[2][2048];   // 32 s-rows x 64 e (swizzled)
  __shared__ __align__(16) f16_t v_t[2][2048];   // 64 d-rows x 32 s (linear)
  __shared__ __align__(16) f16_t wbuf[4][16 * 40];  // per-wave w, PAD 40

  int bh = blockIdx.x & 63;   // XCD swizzle: all q-blocks of a head co-located
  int qb = blockIdx.x >> 6;
  int b = bh >> 3, h = bh & 7;
  int tid = threadIdx.x;
  int wave = tid >> 6, lane = tid & 63;
  int g = lane >> 4, n = lane & 15;

  const f16_t* qf_b = qf + ((size_t)bh * L_ + qb * 64) * 64;
  const f16_t* kf_b = kf + (size_t)bh * S_ * 64;
  const f16_t* vt_b = vt + (size_t)bh * 32 * 2048;

  // Q A-fragments (swizzled chunk addressing); k-chunk g and g^4 (^32 elems)
  int arow = wave * 16 + n;
  int qoff = arow * 64 + ((g ^ (n & 7)) << 3);
  f16x8 qa0 = *(const f16x8*)(qf_b + qoff);
  f16x8 qa1 = *(const f16x8*)(qf_b + (qoff ^ 32));

  // B-frag offset in a K tile (row n; row n+16 at +1024); same swizzle
  int koff = n * 64 + ((g ^ (n & 7)) << 3);
  int lds_o = tid * 8;  // lane-linear glds staging slot (16B/thread)

  const f32x4 fzero = {0.f, 0.f, 0.f, 0.f};
  f32x4 acc2 = fzero, acc4 = fzero, mx = fzero;

  // ---- PASS 1: row stats, barrier-free (K direct from global/L2) ----
  const f16_t* kg = kf_b;
#pragma unroll 2
  for (int t = 0; t < 32; ++t) {
    f16x8 b00 = *(const f16x8*)(kg + koff);
    f16x8 b01 = *(const f16x8*)(kg + (koff ^ 32));
    f16x8 b10 = *(const f16x8*)(kg + koff + 1024);
    f16x8 b11 = *(const f16x8*)(kg + (koff ^ 32) + 1024);
    kg += 2048;
    f32x4 sc0 = MFMA16F(qa0, b00, fzero);
    sc0 = MFMA16F(qa1, b01, sc0);
    f32x4 sc1 = MFMA16F(qa0, b10, fzero);
    sc1 = MFMA16F(qa1, b11, sc1);
    f32x4 t0 = sc0 * sc0, t1 = sc1 * sc1;     // v_pk_mul_f32
    acc2 += t0 + t1;                          // v_pk_add_f32
    acc4 += t0 * t0;                          // v_pk_fma_f32 (contracted)
    acc4 += t1 * t1;
    mx = __builtin_elementwise_max(mx, __builtin_elementwise_max(t0, t1));
  }
  float a2[4], a4[4], m2[4];
#pragma unroll
  for (int r = 0; r < 4; ++r) { a2[r] = acc2[r]; a4[r] = acc4[r]; m2[r] = mx[r]; }
#pragma unroll
  for (int off = 1; off < 16; off <<= 1)
#pragma unroll
    for (int r = 0; r < 4; ++r) {
      a2[r] += __shfl_xor(a2[r], off, 64);
      a4[r] += __shfl_xor(a4[r], off, 64);
      m2[r] = fmaxf(m2[r], __shfl_xor(m2[r], off, 64));
    }
  const float LOG2E = 1.44269504f;
  f32x4 c2v, cm2v;
#pragma unroll
  for (int r = 0; r < 4; ++r) {
    float cr = (a4[r] > 0.f) ? (sqrtf(a2[r] / a4[r]) * LOG2E) : 0.f;
    c2v[r] = cr;
    cm2v[r] = cr * m2[r];
  }

  // ---- PASS 2: fp16 scores -> w -> PV (glds double-buffer, 1 barrier/tile)
  f32x4 pv[4];
#pragma unroll
  for (int dg = 0; dg < 4; ++dg) pv[dg] = fzero;
  f32x4 denv = fzero;
  f16_t* wb = wbuf[wave];

  GLDS16(kf_b + lds_o, &k_t[0][lds_o]);
  GLDS16(vt_b + lds_o, &v_t[0][lds_o]);
  for (int t = 0; t < 32; ++t) {
    __syncthreads();  // drains glds -> tile t ready
    if (t < 31) {
      int go = (t + 1) * 2048 + lds_o;
      int bs = (t + 1) & 1;
      GLDS16(kf_b + go, &k_t[bs][lds_o]);
      GLDS16(vt_b + go, &v_t[bs][lds_o]);
    }
    const f16_t* kt = k_t[t & 1];
    const f16_t* vl = v_t[t & 1];
    // V B-frags issued early (independent of score chain)
    f16x8 vb[4];
#pragma unroll
    for (int dg = 0; dg < 4; ++dg)
      vb[dg] = *(const f16x8*)(vl + n * 32 + dg * 512 + g * 8);
    f16x8 b00 = *(const f16x8*)(kt + koff);
    f16x8 b01 = *(const f16x8*)(kt + (koff ^ 32));
    f16x8 b10 = *(const f16x8*)(kt + koff + 1024);
    f16x8 b11 = *(const f16x8*)(kt + (koff ^ 32) + 1024);
    f32x4 sc0 = MFMA16F(qa0, b00, fzero);
    sc0 = MFMA16F(qa1, b01, sc0);
    f32x4 sc1 = MFMA16F(qa0, b10, fzero);
    sc1 = MFMA16F(qa1, b11, sc1);
    // w = 2^(c2*s^2 - c2*M), vectorized exponent math + raw v_exp_f32
    f32x4 e0 = sc0 * sc0 * c2v - cm2v;        // v_pk_mul/fma
    f32x4 e1 = sc1 * sc1 * c2v - cm2v;
    f32x4 w0, w1;
#pragma unroll
    for (int r = 0; r < 4; ++r) { w0[r] = EXP2(e0[r]); w1[r] = EXP2(e1[r]); }
    denv += w0 + w1;
#pragma unroll
    for (int r = 0; r < 4; ++r) {
      wb[(g * 4 + r) * 40 + n] = (f16_t)w0[r];
      wb[(g * 4 + r) * 40 + 16 + n] = (f16_t)w1[r];
    }
    f16x8 wa = *(const f16x8*)(wb + n * 40 + g * 8);  // same-wave, in-order
#pragma unroll
    for (int dg = 0; dg < 4; ++dg) pv[dg] = MFMA16F(wa, vb[dg], pv[dg]);
  }
  // denominator reduce + normalize + store [B,L,H,D]
  float den[4];
#pragma unroll
  for (int r = 0; r < 4; ++r) den[r] = denv[r];
#pragma unroll
  for (int off = 1; off < 16; off <<= 1)
#pragma unroll
    for (int r = 0; r < 4; ++r) den[r] += __shfl_xor(den[r], off, 64);
#pragma unroll
  for (int r = 0; r < 4; ++r) {
    float inv = 1.f / den[r];
    int l = qb * 64 + wave * 16 + g * 4 + r;
    float* op = out + (((size_t)b * L_ + l) * H_ + h) * D_;
#pragma unroll
    for (int dg = 0; dg < 4; ++dg) op[dg * 16 + n] = pv[dg][r] * inv;
  }
}

extern "C" void kernel_launch(void* const* d_in, const int* in_sizes, int n_in,
                              void* d_out, int out_size, void* d_ws, size_t ws_size,
                              hipStream_t stream) {
  const float* q = (const float*)d_in[0];
  const float* k = (const float*)d_in[1];
  const float* v = (const float*)d_in[2];
  // d_in[3] (attn_mask) is all-False -> unused
  float* out = (float*)d_out;

  const size_t NE = (size_t)B_ * L_ * H_ * E_;  // 4,194,304 elems
  f16_t* qf = (f16_t*)d_ws;                     // ws usage: 3*NE*2B = 24 MB
  f16_t* kf = qf + NE;
  f16_t* vt = kf + NE;

  prep_kernel<<<8192 + 2048, 256, 0, stream>>>(q, k, v, qf, kf, vt);
  attn_kernel<<<BH_ * (L_ / 64), 256, 0, stream>>>(qf, kf, vt, out);
}